// Round 1
// baseline (171.631 us; speedup 1.0000x reference)
//
#include <hip/hip_runtime.h>
#include <hip/hip_bf16.h>

#define FEATURES 256
#define SYMBOLS  1024
#define NPIX     65536        // 16*64*64
#define M_TILE   128
#define THREADS  256
#define AS_BYTES 65536        // 128 rows * 256 bf16 (512 B), XOR-swizzled
#define BS_BYTES 16384        // 128 n-rows * 64 bf16 (128 B), XOR-swizzled
#define SMEM_BYTES (AS_BYTES + BS_BYTES)   // 80 KB -> 2 blocks/CU

typedef float  f32x4  __attribute__((ext_vector_type(4)));
typedef __bf16 bf16x4 __attribute__((ext_vector_type(4)));
typedef __bf16 bf16x8 __attribute__((ext_vector_type(8)));

// ---- prep: W fp32 -> bf16 (ws), wnorm = ||w_s||^2 (ws), zero deviation slot ----
__global__ __launch_bounds__(64) void vq_prep(const float* __restrict__ W,
                                              __bf16* __restrict__ Wb,
                                              float* __restrict__ wnorm,
                                              float* __restrict__ devslot) {
    int s = blockIdx.x;
    int lane = threadIdx.x;
    f32x4 v = ((const f32x4*)(W + (size_t)s * FEATURES))[lane];
    float ss = v[0]*v[0] + v[1]*v[1] + v[2]*v[2] + v[3]*v[3];
    bf16x4 b;
    b[0] = (__bf16)v[0]; b[1] = (__bf16)v[1]; b[2] = (__bf16)v[2]; b[3] = (__bf16)v[3];
    *(bf16x4*)(Wb + (size_t)s * FEATURES + lane * 4) = b;
    #pragma unroll
    for (int off = 32; off > 0; off >>= 1) ss += __shfl_xor(ss, off);
    if (lane == 0) wnorm[s] = ss;
    if (s == 0 && lane == 0) *devslot = 0.f;
}

// ---- main: fused GEMM-argmin + gather-out + deviation ----
__global__ __launch_bounds__(THREADS, 2) void vq_main(
        const float*  __restrict__ x,
        const float*  __restrict__ W,
        const __bf16* __restrict__ Wb,
        const float*  __restrict__ wnorm,
        float*        __restrict__ out,
        float*        __restrict__ devslot) {
    extern __shared__ char smem[];
    const int t    = threadIdx.x;
    const int lane = t & 63;
    const int wave = t >> 6;
    const int quad = lane >> 4;
    const int l16  = lane & 15;
    const int wm   = wave >> 1;          // 2x2 wave grid over the 128x128 C tile
    const int wn   = wave & 1;
    const int m0   = blockIdx.x * M_TILE;
    const float scale = 1.25f / (float)((size_t)NPIX * FEATURES);

    // ---- Stage A: x[128][256] fp32 -> bf16 into swizzled LDS; accumulate ||x||^2 ----
    const f32x4* xblk = (const f32x4*)(x + (size_t)m0 * FEATURES);
    float ss = 0.f;
    #pragma unroll 8
    for (int i = 0; i < 32; ++i) {
        int f   = t + i * THREADS;       // float4 index in tile; row is wave-uniform
        int row = f >> 6;
        int k4  = f & 63;
        f32x4 v = xblk[f];
        ss += v[0]*v[0] + v[1]*v[1] + v[2]*v[2] + v[3]*v[3];
        bf16x4 b;
        b[0] = (__bf16)v[0]; b[1] = (__bf16)v[1]; b[2] = (__bf16)v[2]; b[3] = (__bf16)v[3];
        int kb   = k4 >> 1;              // 16B block within row (0..31)
        int phys = kb ^ (row & 7);       // XOR swizzle -> 2-way banks (free)
        *(bf16x4*)(smem + row * 512 + phys * 16 + (k4 & 1) * 8) = b;
    }
    #pragma unroll
    for (int off = 32; off > 0; off >>= 1) ss += __shfl_xor(ss, off);
    if (lane == 0) atomicAdd(devslot, scale * ss);   // per-wave ||x||^2 partial

    __syncthreads();

    // per-lane running argmin: 16 (mi,r) row slots, this lane's column subset only
    float bestv[16];
    int   besti[16];
    #pragma unroll
    for (int j = 0; j < 16; ++j) { bestv[j] = 3.4e38f; besti[j] = 0; }

    char* bs = smem + AS_BYTES;

    for (int nc = 0; nc < 8; ++nc) {     // 8 chunks of 128 symbols
        f32x4 acc[4][4] = {};
        for (int kt = 0; kt < 4; ++kt) { // K = 4 tiles of 64
            __syncthreads();             // previous compute done reading Bs
            #pragma unroll
            for (int j = 0; j < 4; ++j) {
                int fb = t + j * THREADS;   // 1024 16B-blocks: 128 n x 8 kb
                int n  = fb >> 3;
                int kb = fb & 7;
                bf16x8 src = *(const bf16x8*)(Wb + ((size_t)(nc * 128 + n) * FEATURES + kt * 64 + kb * 8));
                *(bf16x8*)(bs + n * 128 + (kb ^ (n & 7)) * 16) = src;
            }
            __syncthreads();
            #pragma unroll
            for (int ks = 0; ks < 2; ++ks) {
                bf16x8 af[4], bfr[4];
                #pragma unroll
                for (int mi = 0; mi < 4; ++mi) {
                    int row = wm * 64 + mi * 16 + l16;
                    int kb  = kt * 8 + ks * 4 + quad;          // 0..31
                    af[mi] = *(const bf16x8*)(smem + row * 512 + (kb ^ (row & 7)) * 16);
                }
                #pragma unroll
                for (int ni = 0; ni < 4; ++ni) {
                    int n  = wn * 64 + ni * 16 + l16;
                    int kb = ks * 4 + quad;                    // 0..7
                    bfr[ni] = *(const bf16x8*)(bs + n * 128 + (kb ^ (n & 7)) * 16);
                }
                #pragma unroll
                for (int mi = 0; mi < 4; ++mi)
                    #pragma unroll
                    for (int ni = 0; ni < 4; ++ni)
                        acc[mi][ni] = __builtin_amdgcn_mfma_f32_16x16x32_bf16(
                            af[mi], bfr[ni], acc[mi][ni], 0, 0, 0);
            }
        }
        // chunk epilogue: per-lane running min (no cross-lane work here)
        float wnv[4]; int nidx[4];
        #pragma unroll
        for (int ni = 0; ni < 4; ++ni) {
            int n = nc * 128 + wn * 64 + ni * 16 + l16;
            wnv[ni]  = wnorm[n];
            nidx[ni] = n;
        }
        #pragma unroll
        for (int mi = 0; mi < 4; ++mi)
            #pragma unroll
            for (int r = 0; r < 4; ++r) {
                int j = mi * 4 + r;
                #pragma unroll
                for (int ni = 0; ni < 4; ++ni) {
                    float v2 = wnv[ni] - 2.f * acc[mi][ni][r];
                    // strict < keeps the earliest index (candidates arrive in increasing n)
                    if (v2 < bestv[j]) { bestv[j] = v2; besti[j] = nidx[ni]; }
                }
            }
    }

    // one cross-lane merge at the end: min over the 16 lanes of each quad
    #pragma unroll
    for (int j = 0; j < 16; ++j) {
        float v = bestv[j]; int idx = besti[j];
        #pragma unroll
        for (int off = 1; off < 16; off <<= 1) {
            float ov = __shfl_xor(v, off);
            int   oi = __shfl_xor(idx, off);
            if (ov < v || (ov == v && oi < idx)) { v = ov; idx = oi; }
        }
        bestv[j] = v; besti[j] = idx;
    }

    __syncthreads();                      // done with As/Bs; alias merge arrays over smem
    float* mval  = (float*)smem;          // [2][128] per-wn candidates
    int*   midx  = (int*)(smem + 1024);   // [2][128]
    int*   codes = (int*)(smem + 2048);   // [128]

    if (l16 == 0) {                       // one writer lane per quad (data is quad-uniform)
        #pragma unroll
        for (int j = 0; j < 16; ++j) {
            int mi = j >> 2, r = j & 3;
            int row = wm * 64 + mi * 16 + quad * 4 + r;
            mval[wn * 128 + row] = bestv[j];
            midx[wn * 128 + row] = besti[j];
        }
    }
    __syncthreads();

    if (t < 128) {                        // waves 0,1: merge wn halves, reduce deviation
        int row = t;
        float v0 = mval[row],     v1 = mval[128 + row];
        int   i0 = midx[row],     i1 = midx[128 + row];
        float bv; int code;
        if (v1 < v0 || (v1 == v0 && i1 < i0)) { bv = v1; code = i1; }
        else                                  { bv = v0; code = i0; }
        codes[row] = code;
        #pragma unroll
        for (int off = 32; off > 0; off >>= 1) bv += __shfl_xor(bv, off);
        if (lane == 0) atomicAdd(devslot, scale * bv);   // Sum(wnorm - 2*S_best)
    }
    __syncthreads();

    // ---- out = W[code] (exact fp32 gather from the original codebook) ----
    f32x4* oblk = (f32x4*)(out + (size_t)m0 * FEATURES);
    #pragma unroll 8
    for (int i = 0; i < 32; ++i) {
        int f    = t + i * THREADS;
        int row  = f >> 6;                // wave-uniform
        int k4   = f & 63;
        int code = codes[row];
        oblk[f] = ((const f32x4*)(W + (size_t)code * FEATURES))[k4];
    }
}

extern "C" void kernel_launch(void* const* d_in, const int* in_sizes, int n_in,
                              void* d_out, int out_size, void* d_ws, size_t ws_size,
                              hipStream_t stream) {
    const float* x = (const float*)d_in[0];
    const float* W = (const float*)d_in[1];
    float* out = (float*)d_out;

    __bf16* Wb    = (__bf16*)d_ws;                                        // 512 KB
    float*  wnorm = (float*)((char*)d_ws + (size_t)SYMBOLS * FEATURES * 2); // 4 KB
    float*  devslot = out + (size_t)NPIX * FEATURES;                      // d_out tail

    // 80 KB dynamic LDS needs the opt-in attribute (idempotent; safe under capture)
    hipFuncSetAttribute(reinterpret_cast<const void*>(vq_main),
                        hipFuncAttributeMaxDynamicSharedMemorySize, SMEM_BYTES);

    vq_prep<<<SYMBOLS, 64, 0, stream>>>(W, Wb, wnorm, devslot);
    vq_main<<<NPIX / M_TILE, THREADS, SMEM_BYTES, stream>>>(x, W, Wb, wnorm, out, devslot);
}